// Round 7
// baseline (17729.478 us; speedup 1.0000x reference)
//
#include <hip/hip_runtime.h>
#include <math.h>

// Problem constants
#define Bv   16
#define NVv  4
#define Cv   768
#define Nv   784
#define QKv  96
#define CDv  3072
#define FDv  3136

static constexpr int PB  = CDv * Nv;   // 2408448 floats per batch plane (== 768*3136)
static constexpr int OBl = Cv * Nv;    // 602112 floats per output-batch plane

static constexpr float FA_SCALE = 1.0f / 56.0f;            // 1/sqrt(3136)
static constexpr float CA_SCALE = 0.0180421959121758f;     // 1/sqrt(3072)

enum { MODE_PLAIN = 0, MODE_SA = 1, MODE_FA = 2, MODE_CA = 3 };

typedef __bf16 bf16x8 __attribute__((ext_vector_type(8)));
typedef unsigned short u16x8 __attribute__((ext_vector_type(8)));
typedef float f32x4 __attribute__((ext_vector_type(4)));

#define LDK 40   // LDS row stride in bf16 elems: 32 + 8 pad (80 B = 5*16B, u16x8 stays 16B-aligned)

// fp32 -> (hi, lo) bf16 pair, RNE. x ≈ hi + lo with ~2^-17 relative error.
__device__ __forceinline__ void f2bf2(float x, unsigned short& h, unsigned short& l)
{
    unsigned int u  = __builtin_bit_cast(unsigned int, x);
    unsigned int hb = (u + 0x7FFFu + ((u >> 16) & 1u)) >> 16;
    h = (unsigned short)hb;
    float hf = __builtin_bit_cast(float, hb << 16);
    float r  = x - hf;
    unsigned int u2 = __builtin_bit_cast(unsigned int, r);
    l = (unsigned short)((u2 + 0x7FFFu + ((u2 >> 16) & 1u)) >> 16);
}

// Stage a 64x32 fp32 tile (rows tm0.., k k0..k0+31) of P into hi/lo bf16 LDS.
// Element (r,k) = P[r*si + k*sk]. Two paths: sk==1 (k-contig) or si==1 (row-contig).
// All call-site M/K are multiples of 8, so guarded 8-runs never straddle bounds.
__device__ __forceinline__ void stage(const float* __restrict__ P, long si, long sk,
                                      int tm0, int Mlim, int k0, int Klim,
                                      unsigned short* __restrict__ Sh,
                                      unsigned short* __restrict__ Sl, int tid)
{
    float x[8];
    if (sk == 1) {
        int row = tid >> 2;          // 0..63
        int kq  = (tid & 3) << 3;    // 0,8,16,24
        int gi = tm0 + row, gk = k0 + kq;
        if (gi < Mlim && gk < Klim) {
            const float4* s = reinterpret_cast<const float4*>(P + (size_t)gi * si + gk);
            float4 a = s[0], b = s[1];
            x[0]=a.x; x[1]=a.y; x[2]=a.z; x[3]=a.w;
            x[4]=b.x; x[5]=b.y; x[6]=b.z; x[7]=b.w;
        } else {
#pragma unroll
            for (int e = 0; e < 8; ++e) x[e] = 0.f;
        }
        u16x8 hv, lv;
#pragma unroll
        for (int e = 0; e < 8; ++e) {
            unsigned short hh, ll; f2bf2(x[e], hh, ll); hv[e] = hh; lv[e] = ll;
        }
        *(u16x8*)&Sh[row * LDK + kq] = hv;
        *(u16x8*)&Sl[row * LDK + kq] = lv;
    } else {
        // row-contiguous (si == 1): element (i0+e, kk) = P[(k0+kk)*sk + tm0+i0+e]
        int kk = tid >> 3;           // 0..31
        int i0 = (tid & 7) << 3;     // 0..56
        int gk = k0 + kk, gi = tm0 + i0;
        if (gi < Mlim && gk < Klim) {
            const float4* s = reinterpret_cast<const float4*>(P + (size_t)gk * sk + gi);
            float4 a = s[0], b = s[1];
            x[0]=a.x; x[1]=a.y; x[2]=a.z; x[3]=a.w;
            x[4]=b.x; x[5]=b.y; x[6]=b.z; x[7]=b.w;
        } else {
#pragma unroll
            for (int e = 0; e < 8; ++e) x[e] = 0.f;
        }
#pragma unroll
        for (int e = 0; e < 8; ++e) {
            unsigned short hh, ll; f2bf2(x[e], hh, ll);
            Sh[(i0 + e) * LDK + kk] = hh;
            Sl[(i0 + e) * LDK + kk] = ll;
        }
    }
}

#define BC(v) __builtin_bit_cast(bf16x8, v)
#define MFMA  __builtin_amdgcn_mfma_f32_16x16x32_bf16

// Split-bf16 MFMA GEMM, 64x64 tile, BK=32, 4 waves (2x2), wave tile 32x32.
//   acc(p,i,j) = sum_k A[p*sAp + i*sAi + k*sAk] * B[p*sBp + j*sBj + k*sBk]
// computed as Ahi*Bhi + Ahi*Blo + Alo*Bhi (fp32 accumulate) ~= fp32-exact.
// Epilogues: PLAIN store / SA residual-write to X / FA,CA atomic scatter into out.
template <int MODE>
__global__ __launch_bounds__(256) void k_mfma(
    const float* __restrict__ A, long sAp, long sAi, long sAk,
    const float* __restrict__ Bm, long sBp, long sBj, long sBk,
    const float* __restrict__ bias, int biasAxis,
    float scale,
    float* __restrict__ Cc, long sCp, long sCi, long sCj,
    int M, int N, int K, int viewIdx,
    const float* __restrict__ gamma, const float* __restrict__ resid)
{
    __shared__ unsigned short AhS[64 * LDK], AlS[64 * LDK];
    __shared__ unsigned short BhS[64 * LDK], BlS[64 * LDK];

    const int p   = blockIdx.z;
    const int tm0 = blockIdx.y * 64;
    const int tn0 = blockIdx.x * 64;
    const int tid = threadIdx.x;

    const int l  = tid & 63;
    const int w  = tid >> 6;       // wave 0..3
    const int wm = w >> 1, wn = w & 1;
    const int lr = l & 15, lg = l >> 4;

    const float* Ap = A  + (size_t)p * sAp;
    const float* Bp = Bm + (size_t)p * sBp;

    f32x4 acc[2][2] = {};

    const int nsteps = (K + 31) >> 5;
    for (int s = 0; s < nsteps; ++s) {
        const int k0 = s << 5;
        stage(Ap, sAi, sAk, tm0, M, k0, K, AhS, AlS, tid);
        stage(Bp, sBj, sBk, tn0, N, k0, K, BhS, BlS, tid);
        __syncthreads();

        u16x8 ah[2], al[2], bh[2], bl[2];
#pragma unroll
        for (int pm = 0; pm < 2; ++pm) {
            int ro = (wm * 32 + pm * 16 + lr) * LDK + lg * 8;
            ah[pm] = *(const u16x8*)&AhS[ro];
            al[pm] = *(const u16x8*)&AlS[ro];
        }
#pragma unroll
        for (int pn = 0; pn < 2; ++pn) {
            int co = (wn * 32 + pn * 16 + lr) * LDK + lg * 8;
            bh[pn] = *(const u16x8*)&BhS[co];
            bl[pn] = *(const u16x8*)&BlS[co];
        }
#pragma unroll
        for (int pm = 0; pm < 2; ++pm)
#pragma unroll
            for (int pn = 0; pn < 2; ++pn) {
                acc[pm][pn] = MFMA(BC(ah[pm]), BC(bh[pn]), acc[pm][pn], 0, 0, 0);
                acc[pm][pn] = MFMA(BC(ah[pm]), BC(bl[pn]), acc[pm][pn], 0, 0, 0);
                acc[pm][pn] = MFMA(BC(al[pm]), BC(bh[pn]), acc[pm][pn], 0, 0, 0);
            }
        __syncthreads();
    }

    // ---- epilogue ----  C/D layout: col = lane&15, row = (lane>>4)*4 + reg
#pragma unroll
    for (int pm = 0; pm < 2; ++pm)
#pragma unroll
        for (int pn = 0; pn < 2; ++pn) {
            f32x4 v4 = acc[pm][pn];
#pragma unroll
            for (int r = 0; r < 4; ++r) {
                int i = tm0 + wm * 32 + pm * 16 + lg * 4 + r;
                int j = tn0 + wn * 32 + pn * 16 + lr;
                if (i >= M || j >= N) continue;
                float v = v4[r];
                if (MODE == MODE_PLAIN) {
                    v *= scale;
                    if (bias) v += bias[biasAxis ? j : i];
                    Cc[(size_t)p * sCp + (size_t)i * sCi + (size_t)j * sCj] = v;
                } else if (MODE == MODE_SA) {
                    // p = batch within this view-chunk; write X[p][viewIdx*768+i][j]
                    float val = gamma[viewIdx] * v +
                                resid[(size_t)p * OBl + (size_t)i * Nv + j];
                    Cc[(size_t)p * PB + (size_t)(viewIdx * Cv + i) * Nv + j] = val;
                } else if (MODE == MODE_FA) {
                    // torch scramble: y0[i][j] -> plane flat j*768+i; fold view into out
                    size_t flat = (size_t)j * 768 + i;
                    int rr = (int)(flat / 784), n = (int)(flat % 784);
                    atomicAdd(&Cc[(size_t)p * OBl + (size_t)(rr % 768) * 784 + n],
                              0.125f * v);
                } else { // MODE_CA
                    size_t f = (size_t)j * 784 + i;
                    int rr = (int)(f % 3072), n = (int)(f / 3072);
                    atomicAdd(&Cc[(size_t)p * OBl + (size_t)(rr % 768) * 784 + n],
                              0.125f * v);
                }
            }
        }
}

// In-place row softmax with pre-scale. One block per row.
__global__ __launch_bounds__(256) void k_softmax(float* __restrict__ data,
                                                 int rowLen, float scale)
{
    size_t row = blockIdx.x;
    float* d = data + row * (size_t)rowLen;
    int tid = threadIdx.x;
    __shared__ float red[4];

    float m = -3.0e38f;
    for (int i = tid; i < rowLen; i += 256) m = fmaxf(m, d[i] * scale);
#pragma unroll
    for (int off = 1; off < 64; off <<= 1) m = fmaxf(m, __shfl_xor(m, off, 64));
    if ((tid & 63) == 0) red[tid >> 6] = m;
    __syncthreads();
    m = fmaxf(fmaxf(red[0], red[1]), fmaxf(red[2], red[3]));
    __syncthreads();

    float s = 0.f;
    for (int i = tid; i < rowLen; i += 256) {
        float e = expf(d[i] * scale - m);
        d[i] = e;
        s += e;
    }
#pragma unroll
    for (int off = 1; off < 64; off <<= 1) s += __shfl_xor(s, off, 64);
    if ((tid & 63) == 0) red[tid >> 6] = s;
    __syncthreads();
    s = red[0] + red[1] + red[2] + red[3];
    float inv = 1.f / s;
    for (int i = tid; i < rowLen; i += 256) d[i] *= inv;
}

// out[b, c, n] = 0.25 * sum_v X[b, v*768 + c, n]   (the telescoped 2X term)
__global__ __launch_bounds__(256) void k_init(float* __restrict__ out,
                                              const float* __restrict__ X)
{
    int i = blockIdx.x * 256 + threadIdx.x;
    int stride = gridDim.x * 256;
    const int total = Bv * OBl;
    for (; i < total; i += stride) {
        int b = i / OBl, r = i % OBl;
        const float* x = X + (size_t)b * PB;
        out[i] = 0.25f * (x[r] + x[r + OBl] + x[r + 2 * OBl] + x[r + 3 * OBl]);
    }
}

// Diagnostic fill (used only when ws_size is insufficient).
__global__ __launch_bounds__(256) void k_fill(float* __restrict__ out, float val, int n)
{
    int i = blockIdx.x * 256 + threadIdx.x;
    int stride = gridDim.x * 256;
    for (; i < n; i += stride) out[i] = val;
}

extern "C" void kernel_launch(void* const* d_in, const int* in_sizes, int n_in,
                              void* d_out, int out_size, void* d_ws, size_t ws_size,
                              hipStream_t stream)
{
    const float* features = (const float*)d_in[0];
    const float* sa_wq = (const float*)d_in[1];
    const float* sa_bq = (const float*)d_in[2];
    const float* sa_wk = (const float*)d_in[3];
    const float* sa_bk = (const float*)d_in[4];
    const float* sa_wv = (const float*)d_in[5];
    const float* sa_bv = (const float*)d_in[6];
    const float* sa_gamma = (const float*)d_in[7];
    const float* ca_wq = (const float*)d_in[8];
    const float* ca_bq = (const float*)d_in[9];
    const float* ca_wk = (const float*)d_in[10];
    const float* ca_bk = (const float*)d_in[11];
    const float* ca_wv = (const float*)d_in[12];
    const float* ca_bv = (const float*)d_in[13];
    const float* fa_wq = (const float*)d_in[14];
    const float* fa_bq = (const float*)d_in[15];
    const float* fa_wk = (const float*)d_in[16];
    const float* fa_bk = (const float*)d_in[17];
    const float* fa_wv = (const float*)d_in[18];
    const float* fa_bv = (const float*)d_in[19];
    float* out = (float*)d_out;

    // ---- Workspace layout (floats), total 137,482,240 fl = ~525 MiB ----
    const size_t PLANE = (size_t)Bv * PB;        // 38,535,168
    const size_t SZ_A64 = (size_t)Bv * Nv * Nv;  //  9,834,496 (>= 16*768*768 too)
    const size_t SZ_QK  = (size_t)Bv * QKv * Nv; //  1,204,224
    const size_t SZ_V   = (size_t)Bv * OBl;      //  9,633,792

    float* ws  = (float*)d_ws;
    float* X   = ws;                       // [B][3072][784]
    float* T1  = X  + PLANE;               // q / v temp
    float* T2  = T1 + PLANE;               // k temp
    float* A64 = T2 + PLANE;               // attention buffer (chunked)
    float* Qs  = A64 + SZ_A64;
    float* Ks  = Qs + SZ_QK;
    float* Vs  = Ks + SZ_QK;

    const size_t REQ_BYTES = (3 * PLANE + SZ_A64 + 2 * SZ_QK + SZ_V) * sizeof(float);
    if (ws_size < REQ_BYTES) {
        // Unmistakable diagnostic: absmax ~= 12345 means "workspace too small".
        k_fill<<<dim3(1024), 256, 0, stream>>>(out, 12345.0f, Bv * OBl);
        return;
    }

    // ---------------- Stage 1: per-view self-attention (chunked by view) -------
    for (int g = 0; g < NVv; ++g) {
        const float* feat_g = features + (size_t)g * Bv * OBl;
        // Q[p][96][784] = sa_wq[g] @ xf + bq
        k_mfma<MODE_PLAIN><<<dim3(13, 2, Bv), 256, 0, stream>>>(
            sa_wq + (size_t)g * QKv * Cv, 0, Cv, 1,
            feat_g, OBl, 1, Nv,
            sa_bq + (size_t)g * QKv, 0,
            1.f, Qs, (long)QKv * Nv, Nv, 1,
            QKv, Nv, Cv, 0, nullptr, nullptr);
        // K
        k_mfma<MODE_PLAIN><<<dim3(13, 2, Bv), 256, 0, stream>>>(
            sa_wk + (size_t)g * QKv * Cv, 0, Cv, 1,
            feat_g, OBl, 1, Nv,
            sa_bk + (size_t)g * QKv, 0,
            1.f, Ks, (long)QKv * Nv, Nv, 1,
            QKv, Nv, Cv, 0, nullptr, nullptr);
        // V[p][768][784]
        k_mfma<MODE_PLAIN><<<dim3(13, 12, Bv), 256, 0, stream>>>(
            sa_wv + (size_t)g * Cv * Cv, 0, Cv, 1,
            feat_g, OBl, 1, Nv,
            sa_bv + (size_t)g * Cv, 0,
            1.f, Vs, (long)OBl, Nv, 1,
            Cv, Nv, Cv, 0, nullptr, nullptr);
        // E[p][n][m] = sum_o Q[o][n] K[o][m]   (no scale)
        k_mfma<MODE_PLAIN><<<dim3(13, 13, Bv), 256, 0, stream>>>(
            Qs, (long)QKv * Nv, 1, Nv,
            Ks, (long)QKv * Nv, 1, Nv,
            nullptr, 0,
            1.f, A64, (long)Nv * Nv, Nv, 1,
            Nv, Nv, QKv, 0, nullptr, nullptr);
        k_softmax<<<dim3(Bv * Nv), 256, 0, stream>>>(A64, Nv, 1.f);
        // X[p][g*768+c][m] = gamma[g]*sum_n V[c][n]*attn[m][n] + xf[c][m]
        k_mfma<MODE_SA><<<dim3(13, 12, Bv), 256, 0, stream>>>(
            Vs, (long)OBl, Nv, 1,
            A64, (long)Nv * Nv, Nv, 1,
            nullptr, 0,
            1.f, X, 0, 0, 0,
            Cv, Nv, Nv, g, sa_gamma, feat_g);
    }

    // ---------------- Stage 2: out = 0.25 * sum_v X ----------------
    k_init<<<dim3(2048), 256, 0, stream>>>(out, X);

    // ---------------- Stage 3: feature attention (X viewed [B,768,3136]) -------
    k_mfma<MODE_PLAIN><<<dim3(49, 12, Bv), 256, 0, stream>>>(
        X, PB, FDv, 1,
        fa_wq, 0, FDv, 1,
        fa_bq, 1,
        1.f, T1, PB, FDv, 1,
        Cv, FDv, FDv, 0, nullptr, nullptr);
    k_mfma<MODE_PLAIN><<<dim3(49, 12, Bv), 256, 0, stream>>>(
        X, PB, FDv, 1,
        fa_wk, 0, FDv, 1,
        fa_bk, 1,
        1.f, T2, PB, FDv, 1,
        Cv, FDv, FDv, 0, nullptr, nullptr);
    // E[768][768] = q k^T * FD^-0.5
    k_mfma<MODE_PLAIN><<<dim3(12, 12, Bv), 256, 0, stream>>>(
        T1, PB, FDv, 1,
        T2, PB, FDv, 1,
        nullptr, 0,
        FA_SCALE, A64, (long)Cv * Cv, Cv, 1,
        Cv, Cv, FDv, 0, nullptr, nullptr);
    k_softmax<<<dim3(Bv * Cv), 256, 0, stream>>>(A64, Cv, 1.f);
    // v (overwrites q in T1)
    k_mfma<MODE_PLAIN><<<dim3(49, 12, Bv), 256, 0, stream>>>(
        X, PB, FDv, 1,
        fa_wv, 0, FDv, 1,
        fa_bv, 1,
        1.f, T1, PB, FDv, 1,
        Cv, FDv, FDv, 0, nullptr, nullptr);
    // y0 = attn @ v -> scrambled atomic scatter into out
    k_mfma<MODE_FA><<<dim3(49, 12, Bv), 256, 0, stream>>>(
        A64, (long)Cv * Cv, Cv, 1,
        T1, PB, 1, FDv,
        nullptr, 0,
        1.f, out, 0, 0, 0,
        Cv, FDv, Cv, 0, nullptr, nullptr);

    // ---------------- Stage 4: channel attention (x = X^T per batch) ------------
    k_mfma<MODE_PLAIN><<<dim3(48, 13, Bv), 256, 0, stream>>>(
        X, PB, 1, Nv,
        ca_wq, 0, CDv, 1,
        ca_bq, 1,
        1.f, T1, PB, CDv, 1,
        Nv, CDv, CDv, 0, nullptr, nullptr);
    k_mfma<MODE_PLAIN><<<dim3(48, 13, Bv), 256, 0, stream>>>(
        X, PB, 1, Nv,
        ca_wk, 0, CDv, 1,
        ca_bk, 1,
        1.f, T2, PB, CDv, 1,
        Nv, CDv, CDv, 0, nullptr, nullptr);
    // E[784][784] = q k^T * CD^-0.5
    k_mfma<MODE_PLAIN><<<dim3(13, 13, Bv), 256, 0, stream>>>(
        T1, PB, CDv, 1,
        T2, PB, CDv, 1,
        nullptr, 0,
        CA_SCALE, A64, (long)Nv * Nv, Nv, 1,
        Nv, Nv, CDv, 0, nullptr, nullptr);
    k_softmax<<<dim3(Bv * Nv), 256, 0, stream>>>(A64, Nv, 1.f);
    // v (overwrites q in T1)
    k_mfma<MODE_PLAIN><<<dim3(48, 13, Bv), 256, 0, stream>>>(
        X, PB, 1, Nv,
        ca_wv, 0, CDv, 1,
        ca_bv, 1,
        1.f, T1, PB, CDv, 1,
        Nv, CDv, CDv, 0, nullptr, nullptr);
    // y0 = attn @ v -> scrambled atomic scatter into out
    k_mfma<MODE_CA><<<dim3(48, 13, Bv), 256, 0, stream>>>(
        A64, (long)Nv * Nv, Nv, 1,
        T1, PB, 1, CDv,
        nullptr, 0,
        1.f, out, 0, 0, 0,
        Nv, CDv, Nv, 0, nullptr, nullptr);
}

// Round 9
// 15601.537 us; speedup vs baseline: 1.1364x; 1.1364x over previous
//
#include <hip/hip_runtime.h>
#include <math.h>

// Problem constants
#define Bv   16
#define NVv  4
#define Cv   768
#define Nv   784
#define QKv  96
#define CDv  3072
#define FDv  3136

static constexpr int PB  = CDv * Nv;   // 2408448 floats per batch plane (== 768*3136)
static constexpr int OBl = Cv * Nv;    // 602112 floats per output-batch plane

static constexpr float FA_SCALE = 1.0f / 56.0f;            // 1/sqrt(3136)
static constexpr float CA_SCALE = 0.0180421959121758f;     // 1/sqrt(3072)

enum { MODE_PLAIN = 0, MODE_SA = 1, MODE_FA = 2, MODE_CA = 3 };

typedef __bf16 bf16x8 __attribute__((ext_vector_type(8)));
typedef unsigned short u16x8 __attribute__((ext_vector_type(8)));
typedef float f32x4 __attribute__((ext_vector_type(4)));

#define LDK 40   // LDS row stride in bf16 elems: 32 + 8 pad (80 B = 5*16B, u16x8 stays 16B-aligned)

// fp32 -> (hi, lo) bf16 pair, RNE. x ≈ hi + lo with ~2^-17 relative error.
__device__ __forceinline__ void f2bf2(float x, unsigned short& h, unsigned short& l)
{
    unsigned int u  = __builtin_bit_cast(unsigned int, x);
    unsigned int hb = (u + 0x7FFFu + ((u >> 16) & 1u)) >> 16;
    h = (unsigned short)hb;
    float hf = __builtin_bit_cast(float, hb << 16);
    float r  = x - hf;
    unsigned int u2 = __builtin_bit_cast(unsigned int, r);
    l = (unsigned short)((u2 + 0x7FFFu + ((u2 >> 16) & 1u)) >> 16);
}

// Stage a 64x32 fp32 tile (rows tm0.., k k0..k0+31) of P into hi/lo bf16 LDS.
// Element (r,k) = P[r*si + k*sk]. Thread mapping identical for both paths:
// each thread owns (row = tid>>2, k-block kq = (tid&3)*8) and writes ONE u16x8
// per LDS buffer. k-block index is XOR-swizzled by (row>>3)&3; reads use the
// same swizzle, so both stay single 16B ops at <=2 lanes/bank (free).
// All call-site K are multiples of 8, so guarded 8-runs never straddle bounds.
__device__ __forceinline__ void stage(const float* __restrict__ P, long si, long sk,
                                      int tm0, int Mlim, int k0, int Klim,
                                      unsigned short* __restrict__ Sh,
                                      unsigned short* __restrict__ Sl, int tid)
{
    float x[8];
    const int row = tid >> 2;          // 0..63
    const int kq  = (tid & 3) << 3;    // 0,8,16,24
    const int gi  = tm0 + row;
    const int gk  = k0 + kq;

    if (gi < Mlim && gk < Klim) {
        if (sk == 1) {
            // k-contiguous: two float4 loads
            const float4* s = reinterpret_cast<const float4*>(P + (size_t)gi * si + gk);
            float4 a = s[0], b = s[1];
            x[0]=a.x; x[1]=a.y; x[2]=a.z; x[3]=a.w;
            x[4]=b.x; x[5]=b.y; x[6]=b.z; x[7]=b.w;
        } else {
            // i-contiguous (si==1): strided gather along k; wave still forms
            // 64B-contiguous segments across lanes at each e.
#pragma unroll
            for (int e = 0; e < 8; ++e)
                x[e] = P[(size_t)(gk + e) * sk + gi];
        }
    } else {
#pragma unroll
        for (int e = 0; e < 8; ++e) x[e] = 0.f;
    }

    u16x8 hv, lv;
#pragma unroll
    for (int e = 0; e < 8; ++e) {
        unsigned short hh, ll; f2bf2(x[e], hh, ll); hv[e] = hh; lv[e] = ll;
    }
    const int dst = row * LDK + ((((kq >> 3) ^ ((row >> 3) & 3))) << 3);
    *(u16x8*)&Sh[dst] = hv;
    *(u16x8*)&Sl[dst] = lv;
}

#define BC(v) __builtin_bit_cast(bf16x8, v)
#define MFMA  __builtin_amdgcn_mfma_f32_16x16x32_bf16

// Split-bf16 MFMA GEMM, 64x64 tile, BK=32, 4 waves (2x2), wave tile 32x32.
//   acc(p,i,j) = sum_k A[p*sAp + i*sAi + k*sAk] * B[p*sBp + j*sBj + k*sBk]
// computed as Ahi*Bhi + Ahi*Blo + Alo*Bhi (fp32 accumulate) ~= fp32-exact.
// Epilogues: PLAIN store / SA residual-write to X / FA,CA atomic scatter into out.
template <int MODE>
__global__ __launch_bounds__(256) void k_mfma(
    const float* __restrict__ A, long sAp, long sAi, long sAk,
    const float* __restrict__ Bm, long sBp, long sBj, long sBk,
    const float* __restrict__ bias, int biasAxis,
    float scale,
    float* __restrict__ Cc, long sCp, long sCi, long sCj,
    int M, int N, int K, int viewIdx,
    const float* __restrict__ gamma, const float* __restrict__ resid)
{
    __shared__ unsigned short AhS[64 * LDK], AlS[64 * LDK];
    __shared__ unsigned short BhS[64 * LDK], BlS[64 * LDK];

    const int p   = blockIdx.z;
    const int tm0 = blockIdx.y * 64;
    const int tn0 = blockIdx.x * 64;
    const int tid = threadIdx.x;

    const int l  = tid & 63;
    const int w  = tid >> 6;       // wave 0..3
    const int wm = w >> 1, wn = w & 1;
    const int lr = l & 15, lg = l >> 4;

    const float* Ap = A  + (size_t)p * sAp;
    const float* Bp = Bm + (size_t)p * sBp;

    f32x4 acc[2][2] = {};

    const int nsteps = (K + 31) >> 5;
    for (int s = 0; s < nsteps; ++s) {
        const int k0 = s << 5;
        stage(Ap, sAi, sAk, tm0, M, k0, K, AhS, AlS, tid);
        stage(Bp, sBj, sBk, tn0, N, k0, K, BhS, BlS, tid);
        __syncthreads();

        u16x8 ah[2], al[2], bh[2], bl[2];
#pragma unroll
        for (int pm = 0; pm < 2; ++pm) {
            int rowA = wm * 32 + pm * 16 + lr;
            int ro = rowA * LDK + ((lg ^ ((rowA >> 3) & 3)) << 3);
            ah[pm] = *(const u16x8*)&AhS[ro];
            al[pm] = *(const u16x8*)&AlS[ro];
        }
#pragma unroll
        for (int pn = 0; pn < 2; ++pn) {
            int rowB = wn * 32 + pn * 16 + lr;
            int co = rowB * LDK + ((lg ^ ((rowB >> 3) & 3)) << 3);
            bh[pn] = *(const u16x8*)&BhS[co];
            bl[pn] = *(const u16x8*)&BlS[co];
        }
#pragma unroll
        for (int pm = 0; pm < 2; ++pm)
#pragma unroll
            for (int pn = 0; pn < 2; ++pn) {
                acc[pm][pn] = MFMA(BC(ah[pm]), BC(bh[pn]), acc[pm][pn], 0, 0, 0);
                acc[pm][pn] = MFMA(BC(ah[pm]), BC(bl[pn]), acc[pm][pn], 0, 0, 0);
                acc[pm][pn] = MFMA(BC(al[pm]), BC(bh[pn]), acc[pm][pn], 0, 0, 0);
            }
        __syncthreads();
    }

    // ---- epilogue ----  C/D layout: col = lane&15, row = (lane>>4)*4 + reg
#pragma unroll
    for (int pm = 0; pm < 2; ++pm)
#pragma unroll
        for (int pn = 0; pn < 2; ++pn) {
            f32x4 v4 = acc[pm][pn];
#pragma unroll
            for (int r = 0; r < 4; ++r) {
                int i = tm0 + wm * 32 + pm * 16 + lg * 4 + r;
                int j = tn0 + wn * 32 + pn * 16 + lr;
                if (i >= M || j >= N) continue;
                float v = v4[r];
                if (MODE == MODE_PLAIN) {
                    v *= scale;
                    if (bias) v += bias[biasAxis ? j : i];
                    Cc[(size_t)p * sCp + (size_t)i * sCi + (size_t)j * sCj] = v;
                } else if (MODE == MODE_SA) {
                    // p = batch within this view-chunk; write X[p][viewIdx*768+i][j]
                    float val = gamma[viewIdx] * v +
                                resid[(size_t)p * OBl + (size_t)i * Nv + j];
                    Cc[(size_t)p * PB + (size_t)(viewIdx * Cv + i) * Nv + j] = val;
                } else if (MODE == MODE_FA) {
                    // torch scramble: y0[i][j] -> plane flat j*768+i; fold view into out
                    size_t flat = (size_t)j * 768 + i;
                    int rr = (int)(flat / 784), n = (int)(flat % 784);
                    atomicAdd(&Cc[(size_t)p * OBl + (size_t)(rr % 768) * 784 + n],
                              0.125f * v);
                } else { // MODE_CA
                    size_t f = (size_t)j * 784 + i;
                    int rr = (int)(f % 3072), n = (int)(f / 3072);
                    atomicAdd(&Cc[(size_t)p * OBl + (size_t)(rr % 768) * 784 + n],
                              0.125f * v);
                }
            }
        }
}

// In-place row softmax with pre-scale. One block per row.
__global__ __launch_bounds__(256) void k_softmax(float* __restrict__ data,
                                                 int rowLen, float scale)
{
    size_t row = blockIdx.x;
    float* d = data + row * (size_t)rowLen;
    int tid = threadIdx.x;
    __shared__ float red[4];

    float m = -3.0e38f;
    for (int i = tid; i < rowLen; i += 256) m = fmaxf(m, d[i] * scale);
#pragma unroll
    for (int off = 1; off < 64; off <<= 1) m = fmaxf(m, __shfl_xor(m, off, 64));
    if ((tid & 63) == 0) red[tid >> 6] = m;
    __syncthreads();
    m = fmaxf(fmaxf(red[0], red[1]), fmaxf(red[2], red[3]));
    __syncthreads();

    float s = 0.f;
    for (int i = tid; i < rowLen; i += 256) {
        float e = expf(d[i] * scale - m);
        d[i] = e;
        s += e;
    }
#pragma unroll
    for (int off = 1; off < 64; off <<= 1) s += __shfl_xor(s, off, 64);
    if ((tid & 63) == 0) red[tid >> 6] = s;
    __syncthreads();
    s = red[0] + red[1] + red[2] + red[3];
    float inv = 1.f / s;
    for (int i = tid; i < rowLen; i += 256) d[i] *= inv;
}

// out[b, c, n] = 0.25 * sum_v X[b, v*768 + c, n]   (the telescoped 2X term)
__global__ __launch_bounds__(256) void k_init(float* __restrict__ out,
                                              const float* __restrict__ X)
{
    int i = blockIdx.x * 256 + threadIdx.x;
    int stride = gridDim.x * 256;
    const int total = Bv * OBl;
    for (; i < total; i += stride) {
        int b = i / OBl, r = i % OBl;
        const float* x = X + (size_t)b * PB;
        out[i] = 0.25f * (x[r] + x[r + OBl] + x[r + 2 * OBl] + x[r + 3 * OBl]);
    }
}

// Diagnostic fill (used only when ws_size is insufficient).
__global__ __launch_bounds__(256) void k_fill(float* __restrict__ out, float val, int n)
{
    int i = blockIdx.x * 256 + threadIdx.x;
    int stride = gridDim.x * 256;
    for (; i < n; i += stride) out[i] = val;
}

extern "C" void kernel_launch(void* const* d_in, const int* in_sizes, int n_in,
                              void* d_out, int out_size, void* d_ws, size_t ws_size,
                              hipStream_t stream)
{
    const float* features = (const float*)d_in[0];
    const float* sa_wq = (const float*)d_in[1];
    const float* sa_bq = (const float*)d_in[2];
    const float* sa_wk = (const float*)d_in[3];
    const float* sa_bk = (const float*)d_in[4];
    const float* sa_wv = (const float*)d_in[5];
    const float* sa_bv = (const float*)d_in[6];
    const float* sa_gamma = (const float*)d_in[7];
    const float* ca_wq = (const float*)d_in[8];
    const float* ca_bq = (const float*)d_in[9];
    const float* ca_wk = (const float*)d_in[10];
    const float* ca_bk = (const float*)d_in[11];
    const float* ca_wv = (const float*)d_in[12];
    const float* ca_bv = (const float*)d_in[13];
    const float* fa_wq = (const float*)d_in[14];
    const float* fa_bq = (const float*)d_in[15];
    const float* fa_wk = (const float*)d_in[16];
    const float* fa_bk = (const float*)d_in[17];
    const float* fa_wv = (const float*)d_in[18];
    const float* fa_bv = (const float*)d_in[19];
    float* out = (float*)d_out;

    // ---- Workspace layout (floats), total 137,482,240 fl = ~525 MiB ----
    const size_t PLANE = (size_t)Bv * PB;        // 38,535,168
    const size_t SZ_A64 = (size_t)Bv * Nv * Nv;  //  9,834,496 (>= 16*768*768 too)
    const size_t SZ_QK  = (size_t)Bv * QKv * Nv; //  1,204,224
    const size_t SZ_V   = (size_t)Bv * OBl;      //  9,633,792

    float* ws  = (float*)d_ws;
    float* X   = ws;                       // [B][3072][784]
    float* T1  = X  + PLANE;               // q / v temp
    float* T2  = T1 + PLANE;               // k temp
    float* A64 = T2 + PLANE;               // attention buffer (chunked)
    float* Qs  = A64 + SZ_A64;
    float* Ks  = Qs + SZ_QK;
    float* Vs  = Ks + SZ_QK;

    const size_t REQ_BYTES = (3 * PLANE + SZ_A64 + 2 * SZ_QK + SZ_V) * sizeof(float);
    if (ws_size < REQ_BYTES) {
        // Unmistakable diagnostic: absmax ~= 12345 means "workspace too small".
        k_fill<<<dim3(1024), 256, 0, stream>>>(out, 12345.0f, Bv * OBl);
        return;
    }

    // ---------------- Stage 1: per-view self-attention (chunked by view) -------
    for (int g = 0; g < NVv; ++g) {
        const float* feat_g = features + (size_t)g * Bv * OBl;
        // Q[p][96][784] = sa_wq[g] @ xf + bq
        k_mfma<MODE_PLAIN><<<dim3(13, 2, Bv), 256, 0, stream>>>(
            sa_wq + (size_t)g * QKv * Cv, 0, Cv, 1,
            feat_g, OBl, 1, Nv,
            sa_bq + (size_t)g * QKv, 0,
            1.f, Qs, (long)QKv * Nv, Nv, 1,
            QKv, Nv, Cv, 0, nullptr, nullptr);
        // K
        k_mfma<MODE_PLAIN><<<dim3(13, 2, Bv), 256, 0, stream>>>(
            sa_wk + (size_t)g * QKv * Cv, 0, Cv, 1,
            feat_g, OBl, 1, Nv,
            sa_bk + (size_t)g * QKv, 0,
            1.f, Ks, (long)QKv * Nv, Nv, 1,
            QKv, Nv, Cv, 0, nullptr, nullptr);
        // V[p][768][784]
        k_mfma<MODE_PLAIN><<<dim3(13, 12, Bv), 256, 0, stream>>>(
            sa_wv + (size_t)g * Cv * Cv, 0, Cv, 1,
            feat_g, OBl, 1, Nv,
            sa_bv + (size_t)g * Cv, 0,
            1.f, Vs, (long)OBl, Nv, 1,
            Cv, Nv, Cv, 0, nullptr, nullptr);
        // E[p][n][m] = sum_o Q[o][n] K[o][m]   (no scale)
        k_mfma<MODE_PLAIN><<<dim3(13, 13, Bv), 256, 0, stream>>>(
            Qs, (long)QKv * Nv, 1, Nv,
            Ks, (long)QKv * Nv, 1, Nv,
            nullptr, 0,
            1.f, A64, (long)Nv * Nv, Nv, 1,
            Nv, Nv, QKv, 0, nullptr, nullptr);
        k_softmax<<<dim3(Bv * Nv), 256, 0, stream>>>(A64, Nv, 1.f);
        // X[p][g*768+c][m] = gamma[g]*sum_n V[c][n]*attn[m][n] + xf[c][m]
        k_mfma<MODE_SA><<<dim3(13, 12, Bv), 256, 0, stream>>>(
            Vs, (long)OBl, Nv, 1,
            A64, (long)Nv * Nv, Nv, 1,
            nullptr, 0,
            1.f, X, 0, 0, 0,
            Cv, Nv, Nv, g, sa_gamma, feat_g);
    }

    // ---------------- Stage 2: out = 0.25 * sum_v X ----------------
    k_init<<<dim3(2048), 256, 0, stream>>>(out, X);

    // ---------------- Stage 3: feature attention (X viewed [B,768,3136]) -------
    k_mfma<MODE_PLAIN><<<dim3(49, 12, Bv), 256, 0, stream>>>(
        X, PB, FDv, 1,
        fa_wq, 0, FDv, 1,
        fa_bq, 1,
        1.f, T1, PB, FDv, 1,
        Cv, FDv, FDv, 0, nullptr, nullptr);
    k_mfma<MODE_PLAIN><<<dim3(49, 12, Bv), 256, 0, stream>>>(
        X, PB, FDv, 1,
        fa_wk, 0, FDv, 1,
        fa_bk, 1,
        1.f, T2, PB, FDv, 1,
        Cv, FDv, FDv, 0, nullptr, nullptr);
    // E[768][768] = q k^T * FD^-0.5
    k_mfma<MODE_PLAIN><<<dim3(12, 12, Bv), 256, 0, stream>>>(
        T1, PB, FDv, 1,
        T2, PB, FDv, 1,
        nullptr, 0,
        FA_SCALE, A64, (long)Cv * Cv, Cv, 1,
        Cv, Cv, FDv, 0, nullptr, nullptr);
    k_softmax<<<dim3(Bv * Cv), 256, 0, stream>>>(A64, Cv, 1.f);
    // v (overwrites q in T1)
    k_mfma<MODE_PLAIN><<<dim3(49, 12, Bv), 256, 0, stream>>>(
        X, PB, FDv, 1,
        fa_wv, 0, FDv, 1,
        fa_bv, 1,
        1.f, T1, PB, FDv, 1,
        Cv, FDv, FDv, 0, nullptr, nullptr);
    // y0 = attn @ v -> scrambled atomic scatter into out
    k_mfma<MODE_FA><<<dim3(49, 12, Bv), 256, 0, stream>>>(
        A64, (long)Cv * Cv, Cv, 1,
        T1, PB, 1, FDv,
        nullptr, 0,
        1.f, out, 0, 0, 0,
        Cv, FDv, Cv, 0, nullptr, nullptr);

    // ---------------- Stage 4: channel attention (x = X^T per batch) ------------
    k_mfma<MODE_PLAIN><<<dim3(48, 13, Bv), 256, 0, stream>>>(
        X, PB, 1, Nv,
        ca_wq, 0, CDv, 1,
        ca_bq, 1,
        1.f, T1, PB, CDv, 1,
        Nv, CDv, CDv, 0, nullptr, nullptr);
    k_mfma<MODE_PLAIN><<<dim3(48, 13, Bv), 256, 0, stream>>>(
        X, PB, 1, Nv,
        ca_wk, 0, CDv, 1,
        ca_bk, 1,
        1.f, T2, PB, CDv, 1,
        Nv, CDv, CDv, 0, nullptr, nullptr);
    // E[784][784] = q k^T * CD^-0.5
    k_mfma<MODE_PLAIN><<<dim3(13, 13, Bv), 256, 0, stream>>>(
        T1, PB, CDv, 1,
        T2, PB, CDv, 1,
        nullptr, 0,
        CA_SCALE, A64, (long)Nv * Nv, Nv, 1,
        Nv, Nv, CDv, 0, nullptr, nullptr);
    k_softmax<<<dim3(Bv * Nv), 256, 0, stream>>>(A64, Nv, 1.f);
    // v (overwrites q in T1)
    k_mfma<MODE_PLAIN><<<dim3(48, 13, Bv), 256, 0, stream>>>(
        X, PB, 1, Nv,
        ca_wv, 0, CDv, 1,
        ca_bv, 1,
        1.f, T1, PB, CDv, 1,
        Nv, CDv, CDv, 0, nullptr, nullptr);
    // y0 = attn @ v -> scrambled atomic scatter into out
    k_mfma<MODE_CA><<<dim3(48, 13, Bv), 256, 0, stream>>>(
        A64, (long)Nv * Nv, Nv, 1,
        T1, PB, 1, CDv,
        nullptr, 0,
        1.f, out, 0, 0, 0,
        Nv, CDv, Nv, 0, nullptr, nullptr);
}

// Round 11
// 13865.126 us; speedup vs baseline: 1.2787x; 1.1252x over previous
//
#include <hip/hip_runtime.h>
#include <math.h>

// Problem constants
#define Bv   16
#define NVv  4
#define Cv   768
#define Nv   784
#define QKv  96
#define CDv  3072
#define FDv  3136

static constexpr int PB  = CDv * Nv;   // 2408448 floats per batch plane (== 768*3136)
static constexpr int OBl = Cv * Nv;    // 602112 floats per output-batch plane

static constexpr float FA_SCALE = 1.0f / 56.0f;            // 1/sqrt(3136)
static constexpr float CA_SCALE = 0.0180421959121758f;     // 1/sqrt(3072)

enum { MODE_PLAIN = 0, MODE_SA = 1 };

typedef __bf16 bf16x8 __attribute__((ext_vector_type(8)));
typedef unsigned short u16x8 __attribute__((ext_vector_type(8)));
typedef float f32x4 __attribute__((ext_vector_type(4)));

#define LDK 40   // LDS row stride in bf16 elems: 32 + 8 pad (80 B = 5*16B, u16x8 stays 16B-aligned)

// fp32 -> (hi, lo) bf16 pair, RNE. x ≈ hi + lo with ~2^-17 relative error.
__device__ __forceinline__ void f2bf2(float x, unsigned short& h, unsigned short& l)
{
    unsigned int u  = __builtin_bit_cast(unsigned int, x);
    unsigned int hb = (u + 0x7FFFu + ((u >> 16) & 1u)) >> 16;
    h = (unsigned short)hb;
    float hf = __builtin_bit_cast(float, hb << 16);
    float r  = x - hf;
    unsigned int u2 = __builtin_bit_cast(unsigned int, r);
    l = (unsigned short)((u2 + 0x7FFFu + ((u2 >> 16) & 1u)) >> 16);
}

// Stage a 64x32 fp32 tile (rows tm0.., k k0..k0+31) of P into hi/lo bf16 LDS.
// Element (r,k) = P[r*si + k*sk]. Each thread owns (row = tid>>2, kq = (tid&3)*8)
// and writes ONE u16x8 per LDS buffer; k-block index XOR-swizzled by (row>>3)&3.
// Reads use the same swizzle -> both sides stay 16B ops at <=2 lanes/bank (free).
__device__ __forceinline__ void stage(const float* __restrict__ P, long si, long sk,
                                      int tm0, int Mlim, int k0, int Klim,
                                      unsigned short* __restrict__ Sh,
                                      unsigned short* __restrict__ Sl, int tid)
{
    float x[8];
    const int row = tid >> 2;          // 0..63
    const int kq  = (tid & 3) << 3;    // 0,8,16,24
    const int gi  = tm0 + row;
    const int gk  = k0 + kq;

    if (gi < Mlim && gk < Klim) {
        if (sk == 1) {
            const float4* s = reinterpret_cast<const float4*>(P + (size_t)gi * si + gk);
            float4 a = s[0], b = s[1];
            x[0]=a.x; x[1]=a.y; x[2]=a.z; x[3]=a.w;
            x[4]=b.x; x[5]=b.y; x[6]=b.z; x[7]=b.w;
        } else {
#pragma unroll
            for (int e = 0; e < 8; ++e)
                x[e] = P[(size_t)(gk + e) * sk + gi];
        }
    } else {
#pragma unroll
        for (int e = 0; e < 8; ++e) x[e] = 0.f;
    }

    u16x8 hv, lv;
#pragma unroll
    for (int e = 0; e < 8; ++e) {
        unsigned short hh, ll; f2bf2(x[e], hh, ll); hv[e] = hh; lv[e] = ll;
    }
    const int dst = row * LDK + ((((kq >> 3) ^ ((row >> 3) & 3))) << 3);
    *(u16x8*)&Sh[dst] = hv;
    *(u16x8*)&Sl[dst] = lv;
}

#define BC(v) __builtin_bit_cast(bf16x8, v)
#define MFMA  __builtin_amdgcn_mfma_f32_16x16x32_bf16

// Split-bf16 MFMA GEMM, 64x64 tile, BK=32, 4 waves (2x2), wave tile 32x32.
//   acc(p,i,j) = sum_k A[p*sAp + i*sAi + k*sAk] * B[p*sBp + j*sBj + k*sBk]
// computed as Ahi*Bhi + Ahi*Blo + Alo*Bhi (fp32 accumulate) ~= fp32-exact.
template <int MODE>
__global__ __launch_bounds__(256) void k_mfma(
    const float* __restrict__ A, long sAp, long sAi, long sAk,
    const float* __restrict__ Bm, long sBp, long sBj, long sBk,
    const float* __restrict__ bias, int biasAxis,
    float scale,
    float* __restrict__ Cc, long sCp, long sCi, long sCj,
    int M, int N, int K, int viewIdx,
    const float* __restrict__ gamma, const float* __restrict__ resid)
{
    __shared__ unsigned short AhS[64 * LDK], AlS[64 * LDK];
    __shared__ unsigned short BhS[64 * LDK], BlS[64 * LDK];

    const int p   = blockIdx.z;
    const int tm0 = blockIdx.y * 64;
    const int tn0 = blockIdx.x * 64;
    const int tid = threadIdx.x;

    const int l  = tid & 63;
    const int w  = tid >> 6;       // wave 0..3
    const int wm = w >> 1, wn = w & 1;
    const int lr = l & 15, lg = l >> 4;

    const float* Ap = A  + (size_t)p * sAp;
    const float* Bp = Bm + (size_t)p * sBp;

    f32x4 acc[2][2] = {};

    const int nsteps = (K + 31) >> 5;
    for (int s = 0; s < nsteps; ++s) {
        const int k0 = s << 5;
        stage(Ap, sAi, sAk, tm0, M, k0, K, AhS, AlS, tid);
        stage(Bp, sBj, sBk, tn0, N, k0, K, BhS, BlS, tid);
        __syncthreads();

        u16x8 ah[2], al[2], bh[2], bl[2];
#pragma unroll
        for (int pm = 0; pm < 2; ++pm) {
            int rowA = wm * 32 + pm * 16 + lr;
            int ro = rowA * LDK + ((lg ^ ((rowA >> 3) & 3)) << 3);
            ah[pm] = *(const u16x8*)&AhS[ro];
            al[pm] = *(const u16x8*)&AlS[ro];
        }
#pragma unroll
        for (int pn = 0; pn < 2; ++pn) {
            int rowB = wn * 32 + pn * 16 + lr;
            int co = rowB * LDK + ((lg ^ ((rowB >> 3) & 3)) << 3);
            bh[pn] = *(const u16x8*)&BhS[co];
            bl[pn] = *(const u16x8*)&BlS[co];
        }
#pragma unroll
        for (int pm = 0; pm < 2; ++pm)
#pragma unroll
            for (int pn = 0; pn < 2; ++pn) {
                acc[pm][pn] = MFMA(BC(ah[pm]), BC(bh[pn]), acc[pm][pn], 0, 0, 0);
                acc[pm][pn] = MFMA(BC(ah[pm]), BC(bl[pn]), acc[pm][pn], 0, 0, 0);
                acc[pm][pn] = MFMA(BC(al[pm]), BC(bh[pn]), acc[pm][pn], 0, 0, 0);
            }
        __syncthreads();
    }

    // ---- epilogue ----  C/D layout: col = lane&15, row = (lane>>4)*4 + reg
#pragma unroll
    for (int pm = 0; pm < 2; ++pm)
#pragma unroll
        for (int pn = 0; pn < 2; ++pn) {
            f32x4 v4 = acc[pm][pn];
#pragma unroll
            for (int r = 0; r < 4; ++r) {
                int i = tm0 + wm * 32 + pm * 16 + lg * 4 + r;
                int j = tn0 + wn * 32 + pn * 16 + lr;
                if (i >= M || j >= N) continue;
                float v = v4[r];
                if (MODE == MODE_PLAIN) {
                    v *= scale;
                    if (bias) v += bias[biasAxis ? j : i];
                    Cc[(size_t)p * sCp + (size_t)i * sCi + (size_t)j * sCj] = v;
                } else { // MODE_SA
                    // p = batch within this view-chunk; write X[p][viewIdx*768+i][j]
                    float val = gamma[viewIdx] * v +
                                resid[(size_t)p * OBl + (size_t)i * Nv + j];
                    Cc[(size_t)p * PB + (size_t)(viewIdx * Cv + i) * Nv + j] = val;
                }
            }
        }
}

// In-place row softmax with pre-scale. One block per row.
__global__ __launch_bounds__(256) void k_softmax(float* __restrict__ data,
                                                 int rowLen, float scale)
{
    size_t row = blockIdx.x;
    float* d = data + row * (size_t)rowLen;
    int tid = threadIdx.x;
    __shared__ float red[4];

    float m = -3.0e38f;
    for (int i = tid; i < rowLen; i += 256) m = fmaxf(m, d[i] * scale);
#pragma unroll
    for (int off = 1; off < 64; off <<= 1) m = fmaxf(m, __shfl_xor(m, off, 64));
    if ((tid & 63) == 0) red[tid >> 6] = m;
    __syncthreads();
    m = fmaxf(fmaxf(red[0], red[1]), fmaxf(red[2], red[3]));
    __syncthreads();

    float s = 0.f;
    for (int i = tid; i < rowLen; i += 256) {
        float e = expf(d[i] * scale - m);
        d[i] = e;
        s += e;
    }
#pragma unroll
    for (int off = 1; off < 64; off <<= 1) s += __shfl_xor(s, off, 64);
    if ((tid & 63) == 0) red[tid >> 6] = s;
    __syncthreads();
    s = red[0] + red[1] + red[2] + red[3];
    float inv = 1.f / s;
    for (int i = tid; i < rowLen; i += 256) d[i] *= inv;
}

// out[b][c][n] = 0.25*sum_v X[b][v*768+c][n]
//             + 0.125*sum_t Yfa[b][m%768][m/768],  m = (c+768t)*784 + n
// (absorbs the old k_init; out is write-only here).
// Yfa is the FA attention output stored row-major [768][3136] per batch.
__global__ __launch_bounds__(256) void k_fold_fa(float* __restrict__ out,
                                                 const float* __restrict__ X,
                                                 const float* __restrict__ Y)
{
    const int b = blockIdx.y;
    const int c = blockIdx.x;                    // 0..767
    const float* xb = X + (size_t)b * PB;
    const float* yb = Y + (size_t)b * PB;
    float* ob = out + (size_t)b * OBl + (size_t)c * Nv;
    for (int n = threadIdx.x; n < Nv; n += 256) {
        int r = c * Nv + n;
        float s = 0.25f * (xb[r] + xb[r + OBl] + xb[r + 2 * OBl] + xb[r + 3 * OBl]);
        float f = 0.f;
#pragma unroll
        for (int t = 0; t < 4; ++t) {
            int m = (c + 768 * t) * 784 + n;
            f += yb[(size_t)(m % 768) * 3136 + (m / 768)];
        }
        ob[n] = s + 0.125f * f;
    }
}

// out[b][c][n] += 0.125*sum_t Yca[b][f%784][f/784],  f = n*3072 + c + 768t
// Yca is the CA attention output stored row-major [784][3072] per batch.
__global__ __launch_bounds__(256) void k_fold_ca(float* __restrict__ out,
                                                 const float* __restrict__ Y)
{
    const int b = blockIdx.y;
    const int c = blockIdx.x;                    // 0..767
    const float* yb = Y + (size_t)b * PB;
    float* ob = out + (size_t)b * OBl + (size_t)c * Nv;
    for (int n = threadIdx.x; n < Nv; n += 256) {
        float f = 0.f;
#pragma unroll
        for (int t = 0; t < 4; ++t) {
            int fi = n * 3072 + c + 768 * t;
            f += yb[(size_t)(fi % 784) * 3072 + (fi / 784)];
        }
        ob[n] += 0.125f * f;
    }
}

// Diagnostic fill (used only when ws_size is insufficient).
__global__ __launch_bounds__(256) void k_fill(float* __restrict__ out, float val, int n)
{
    int i = blockIdx.x * 256 + threadIdx.x;
    int stride = gridDim.x * 256;
    for (; i < n; i += stride) out[i] = val;
}

extern "C" void kernel_launch(void* const* d_in, const int* in_sizes, int n_in,
                              void* d_out, int out_size, void* d_ws, size_t ws_size,
                              hipStream_t stream)
{
    const float* features = (const float*)d_in[0];
    const float* sa_wq = (const float*)d_in[1];
    const float* sa_bq = (const float*)d_in[2];
    const float* sa_wk = (const float*)d_in[3];
    const float* sa_bk = (const float*)d_in[4];
    const float* sa_wv = (const float*)d_in[5];
    const float* sa_bv = (const float*)d_in[6];
    const float* sa_gamma = (const float*)d_in[7];
    const float* ca_wq = (const float*)d_in[8];
    const float* ca_bq = (const float*)d_in[9];
    const float* ca_wk = (const float*)d_in[10];
    const float* ca_bk = (const float*)d_in[11];
    const float* ca_wv = (const float*)d_in[12];
    const float* ca_bv = (const float*)d_in[13];
    const float* fa_wq = (const float*)d_in[14];
    const float* fa_bq = (const float*)d_in[15];
    const float* fa_wk = (const float*)d_in[16];
    const float* fa_bk = (const float*)d_in[17];
    const float* fa_wv = (const float*)d_in[18];
    const float* fa_bv = (const float*)d_in[19];
    float* out = (float*)d_out;

    // ---- Workspace layout (floats), total ~525 MiB (verified fits, round 7) ----
    const size_t PLANE = (size_t)Bv * PB;        // 38,535,168
    const size_t SZ_A64 = (size_t)Bv * Nv * Nv;  //  9,834,496 (>= 16*768*768 too)
    const size_t SZ_QK  = (size_t)Bv * QKv * Nv; //  1,204,224
    const size_t SZ_V   = (size_t)Bv * OBl;      //  9,633,792

    float* ws  = (float*)d_ws;
    float* X   = ws;                       // [B][3072][784]
    float* T1  = X  + PLANE;               // q / v temp
    float* T2  = T1 + PLANE;               // k temp / PV output temp
    float* A64 = T2 + PLANE;               // attention buffer (chunked)
    float* Qs  = A64 + SZ_A64;
    float* Ks  = Qs + SZ_QK;
    float* Vs  = Ks + SZ_QK;

    const size_t REQ_BYTES = (3 * PLANE + SZ_A64 + 2 * SZ_QK + SZ_V) * sizeof(float);
    if (ws_size < REQ_BYTES) {
        // Unmistakable diagnostic: absmax ~= 12345 means "workspace too small".
        k_fill<<<dim3(1024), 256, 0, stream>>>(out, 12345.0f, Bv * OBl);
        return;
    }

    // ---------------- Stage 1: per-view self-attention (chunked by view) -------
    for (int g = 0; g < NVv; ++g) {
        const float* feat_g = features + (size_t)g * Bv * OBl;
        // Q[p][96][784] = sa_wq[g] @ xf + bq
        k_mfma<MODE_PLAIN><<<dim3(13, 2, Bv), 256, 0, stream>>>(
            sa_wq + (size_t)g * QKv * Cv, 0, Cv, 1,
            feat_g, OBl, 1, Nv,
            sa_bq + (size_t)g * QKv, 0,
            1.f, Qs, (long)QKv * Nv, Nv, 1,
            QKv, Nv, Cv, 0, nullptr, nullptr);
        // K
        k_mfma<MODE_PLAIN><<<dim3(13, 2, Bv), 256, 0, stream>>>(
            sa_wk + (size_t)g * QKv * Cv, 0, Cv, 1,
            feat_g, OBl, 1, Nv,
            sa_bk + (size_t)g * QKv, 0,
            1.f, Ks, (long)QKv * Nv, Nv, 1,
            QKv, Nv, Cv, 0, nullptr, nullptr);
        // V[p][768][784]
        k_mfma<MODE_PLAIN><<<dim3(13, 12, Bv), 256, 0, stream>>>(
            sa_wv + (size_t)g * Cv * Cv, 0, Cv, 1,
            feat_g, OBl, 1, Nv,
            sa_bv + (size_t)g * Cv, 0,
            1.f, Vs, (long)OBl, Nv, 1,
            Cv, Nv, Cv, 0, nullptr, nullptr);
        // E[p][n][m] = sum_o Q[o][n] K[o][m]   (no scale)
        k_mfma<MODE_PLAIN><<<dim3(13, 13, Bv), 256, 0, stream>>>(
            Qs, (long)QKv * Nv, 1, Nv,
            Ks, (long)QKv * Nv, 1, Nv,
            nullptr, 0,
            1.f, A64, (long)Nv * Nv, Nv, 1,
            Nv, Nv, QKv, 0, nullptr, nullptr);
        k_softmax<<<dim3(Bv * Nv), 256, 0, stream>>>(A64, Nv, 1.f);
        // X[p][g*768+c][m] = gamma[g]*sum_n V[c][n]*attn[m][n] + xf[c][m]
        k_mfma<MODE_SA><<<dim3(13, 12, Bv), 256, 0, stream>>>(
            Vs, (long)OBl, Nv, 1,
            A64, (long)Nv * Nv, Nv, 1,
            nullptr, 0,
            1.f, X, 0, 0, 0,
            Cv, Nv, Nv, g, sa_gamma, feat_g);
    }

    // ---------------- Stage 2: feature attention (X viewed [B,768,3136]) -------
    k_mfma<MODE_PLAIN><<<dim3(49, 12, Bv), 256, 0, stream>>>(
        X, PB, FDv, 1,
        fa_wq, 0, FDv, 1,
        fa_bq, 1,
        1.f, T1, PB, FDv, 1,
        Cv, FDv, FDv, 0, nullptr, nullptr);
    k_mfma<MODE_PLAIN><<<dim3(49, 12, Bv), 256, 0, stream>>>(
        X, PB, FDv, 1,
        fa_wk, 0, FDv, 1,
        fa_bk, 1,
        1.f, T2, PB, FDv, 1,
        Cv, FDv, FDv, 0, nullptr, nullptr);
    // E[768][768] = q k^T * FD^-0.5
    k_mfma<MODE_PLAIN><<<dim3(12, 12, Bv), 256, 0, stream>>>(
        T1, PB, FDv, 1,
        T2, PB, FDv, 1,
        nullptr, 0,
        FA_SCALE, A64, (long)Cv * Cv, Cv, 1,
        Cv, Cv, FDv, 0, nullptr, nullptr);
    k_softmax<<<dim3(Bv * Cv), 256, 0, stream>>>(A64, Cv, 1.f);
    // v (overwrites q in T1)
    k_mfma<MODE_PLAIN><<<dim3(49, 12, Bv), 256, 0, stream>>>(
        X, PB, FDv, 1,
        fa_wv, 0, FDv, 1,
        fa_bv, 1,
        1.f, T1, PB, FDv, 1,
        Cv, FDv, FDv, 0, nullptr, nullptr);
    // y0 = attn @ v -> plain coalesced store [768][3136] into T2 (k is dead)
    k_mfma<MODE_PLAIN><<<dim3(49, 12, Bv), 256, 0, stream>>>(
        A64, (long)Cv * Cv, Cv, 1,
        T1, PB, 1, FDv,
        nullptr, 0,
        1.f, T2, PB, FDv, 1,
        Cv, FDv, Cv, 0, nullptr, nullptr);
    // out = 0.25*sum_v X + 0.125*fold(FA)   (coalesced writes, gather reads L2/L3)
    k_fold_fa<<<dim3(Cv, Bv), 256, 0, stream>>>(out, X, T2);

    // ---------------- Stage 3: channel attention (x = X^T per batch) ------------
    k_mfma<MODE_PLAIN><<<dim3(48, 13, Bv), 256, 0, stream>>>(
        X, PB, 1, Nv,
        ca_wq, 0, CDv, 1,
        ca_bq, 1,
        1.f, T1, PB, CDv, 1,
        Nv, CDv, CDv, 0, nullptr, nullptr);
    k_mfma<MODE_PLAIN><<<dim3(48, 13, Bv), 256, 0, stream>>>(
        X, PB, 1, Nv,
        ca_wk, 0, CDv, 1,
        ca_bk, 1,
        1.f, T2, PB, CDv, 1,
        Nv, CDv, CDv, 0, nullptr, nullptr);
    // E[784][784] = q k^T * CD^-0.5
    k_mfma<MODE_PLAIN><<<dim3(13, 13, Bv), 256, 0, stream>>>(
        T1, PB, CDv, 1,
        T2, PB, CDv, 1,
        nullptr, 0,
        CA_SCALE, A64, (long)Nv * Nv, Nv, 1,
        Nv, Nv, CDv, 0, nullptr, nullptr);
    k_softmax<<<dim3(Bv * Nv), 256, 0, stream>>>(A64, Nv, 1.f);
    // v (overwrites q in T1)
    k_mfma<MODE_PLAIN><<<dim3(48, 13, Bv), 256, 0, stream>>>(
        X, PB, 1, Nv,
        ca_wv, 0, CDv, 1,
        ca_bv, 1,
        1.f, T1, PB, CDv, 1,
        Nv, CDv, CDv, 0, nullptr, nullptr);
    // y0 = attn @ v -> plain coalesced store [784][3072] into T2 (k is dead)
    k_mfma<MODE_PLAIN><<<dim3(48, 13, Bv), 256, 0, stream>>>(
        A64, (long)Nv * Nv, Nv, 1,
        T1, PB, 1, CDv,
        nullptr, 0,
        1.f, T2, PB, CDv, 1,
        Nv, CDv, Nv, 0, nullptr, nullptr);
    // out += 0.125*fold(CA)
    k_fold_ca<<<dim3(Cv, Bv), 256, 0, stream>>>(out, T2);
}